// Round 6
// baseline (1000.333 us; speedup 1.0000x reference)
//
#include <hip/hip_runtime.h>
#include <cstdint>
#include <cstddef>

// ---------------------------------------------------------------------------
// Pointer-network decoder: B=128 batches decode T=32 steps over N=512 nodes.
// Round 6: block PAIR per batch with SAME-XCD pairing (b <-> b+128; 128%8==0
// so round-robin XCD mapping keeps pairs local -> cheap L2 handoff, fixing
// round 3's cross-XCD regression). 512 thr/block. Per-CU tanh work halves.
// P1 gate-GEMV uses float4 weight loads (4x fewer VMEM issues), P2+P3 fused
// into one single-wave phase (6 barriers/step), gumbel computed on the fly.
// k_setup rebuilt: 64 enc rows/block, 1024 blocks, W1 transposed in LDS.
// All idx-feeding arithmetic keeps the round-2/3/5-verified associations.
// ---------------------------------------------------------------------------

constexpr int B = 128, N = 512, H = 128, T = 32;
constexpr int G4 = 4 * H;  // 512
constexpr float TINYF = 1.17549435e-38f;     // np.finfo(float32).tiny
constexpr uint32_t FLAG_BASE = 0x5AFE0000u;  // slots zeroed by k_setup

// ---- JAX threefry2x32 block cipher (20 rounds) ----------------------------
__host__ __device__ inline uint32_t rotl32(uint32_t v, int d) {
  return (v << d) | (v >> (32 - d));
}

__host__ __device__ inline void tf2x32(uint32_t k0, uint32_t k1,
                                       uint32_t x0, uint32_t x1,
                                       uint32_t& o0, uint32_t& o1) {
  uint32_t ks2 = k0 ^ k1 ^ 0x1BD11BDAu;
  x0 += k0; x1 += k1;
#define TF_R(r) x0 += x1; x1 = rotl32(x1, (r)); x1 ^= x0;
  TF_R(13) TF_R(15) TF_R(26) TF_R(6)
  x0 += k1; x1 += ks2 + 1u;
  TF_R(17) TF_R(29) TF_R(16) TF_R(24)
  x0 += ks2; x1 += k0 + 2u;
  TF_R(13) TF_R(15) TF_R(26) TF_R(6)
  x0 += k0; x1 += k1 + 3u;
  TF_R(17) TF_R(29) TF_R(16) TF_R(24)
  x0 += k1; x1 += ks2 + 4u;
  TF_R(13) TF_R(15) TF_R(26) TF_R(6)
  x0 += ks2; x1 += k0 + 5u;
#undef TF_R
  o0 = x0; o1 = x1;
}

struct KeyArgs { uint32_t k[2 * T]; };  // per-step subkeys, 256 B by value

// Host-side key chain (partitionable split): key0 = (0,42);
// new_key = E_key(0,0), sub = E_key(0,1).
static KeyArgs make_subkeys() {
  KeyArgs ka;
  uint32_t k0 = 0u, k1 = 42u;
  for (int t = 0; t < T; ++t) {
    uint32_t n0, n1, s0, s1;
    tf2x32(k0, k1, 0u, 0u, n0, n1);
    tf2x32(k0, k1, 0u, 1u, s0, s1);
    ka.k[2 * t] = s0; ka.k[2 * t + 1] = s1;
    k0 = n0; k1 = n1;
  }
  return ka;
}

// 32-bit draw i (of 65536) for this step's subkey: w0^w1 of E_sub(0, i)
__device__ inline uint32_t gumbel_bits(uint32_t sk0, uint32_t sk1, int i) {
  uint32_t o0, o1;
  tf2x32(sk0, sk1, 0u, (uint32_t)i, o0, o1);
  return o0 ^ o1;
}

// fast tanh for the score hot loop; abs err ~2e-7 (clamp avoids inf/inf NaN)
__device__ inline float fast_tanh(float x) {
  float cx = fminf(9.0f, fmaxf(-9.0f, x));
  float t = __expf(2.0f * cx);
  return (t - 1.0f) * __builtin_amdgcn_rcpf(t + 1.0f);
}

// agent-scope atomic helpers (pair handoff; safe regardless of XCD placement)
__device__ inline void ag_store(uint32_t* p, uint32_t v) {
  __hip_atomic_store(p, v, __ATOMIC_RELAXED, __HIP_MEMORY_SCOPE_AGENT);
}
__device__ inline uint32_t ag_load(const uint32_t* p) {
  return __hip_atomic_load(p, __ATOMIC_RELAXED, __HIP_MEMORY_SCOPE_AGENT);
}

// ---- setup: blocks 0..1023 = enc_trans (64 rows each, W1 in LDS);
//             blocks 1024..1087 = weight transposes + slot zeroing ----------
__global__ __launch_bounds__(512) void k_setup(
    const float* __restrict__ enc, const float* __restrict__ W1,
    const float* __restrict__ Wih, const float* __restrict__ Whh,
    const float* __restrict__ W2,
    float* __restrict__ encT2, float* __restrict__ WihT,
    float* __restrict__ WhhT, float* __restrict__ W2T,
    uint32_t* __restrict__ slots) {
  __shared__ float w1t[128 * 129];  // padded transpose, ~66 KB

  const int tid = threadIdx.x;
  if (blockIdx.x >= 1024) {
    int base = (blockIdx.x - 1024) * 512 + tid;
    const int stride = 64 * 512;
    for (int i = base; i < H * G4; i += stride) {
      int h = i >> 9, j = i & (G4 - 1);
      WihT[i] = Wih[j * H + h];
      WhhT[i] = Whh[j * H + h];
    }
    for (int i = base; i < H * H; i += stride) {
      int h = i >> 7, k = i & (H - 1);
      W2T[i] = W2[k * H + h];
    }
    for (int i = base; i < 2048; i += stride) slots[i] = 0u;  // no stale flags
    return;
  }
  // transpose W1 into LDS: reads coalesced, writes conflict-free (129 pad)
  for (int i = tid; i < H * H; i += 512) {
    int k = i >> 7, h = i & 127;
    w1t[h * 129 + k] = W1[i];
  }
  __syncthreads();
  const int b = blockIdx.x >> 3;          // 8 blocks per batch
  const int n0 = (blockIdx.x & 7) << 6;   // 64 rows
  const int k = tid & 127, ng = tid >> 7; // ng in 0..3, 16 rows each
  const float* encb = enc + ((size_t)b * N + n0 + ng * 16) * H;
  float acc[16];
#pragma unroll
  for (int j = 0; j < 16; ++j) acc[j] = 0.f;
  for (int h = 0; h < H; h += 4) {
    float w0 = w1t[(h + 0) * 129 + k];
    float w1 = w1t[(h + 1) * 129 + k];
    float w2 = w1t[(h + 2) * 129 + k];
    float w3 = w1t[(h + 3) * 129 + k];
#pragma unroll
    for (int j = 0; j < 16; ++j) {
      const float4 e = *(const float4*)(encb + (size_t)j * H + h);  // broadcast
      acc[j] += w0 * e.x + w1 * e.y + w2 * e.z + w3 * e.w;  // = rounds-2..5 order
    }
  }
  float* dst = encT2 + (size_t)b * H * N + (size_t)k * N + n0 + ng * 16;
#pragma unroll
  for (int q = 0; q < 4; ++q)
    ((float4*)dst)[q] = make_float4(acc[4 * q], acc[4 * q + 1],
                                    acc[4 * q + 2], acc[4 * q + 3]);
}

// ---- main fused decoder: pair (b, b+128) per batch, 512 threads -----------
__global__ __launch_bounds__(512) void k_decode(
    const float* __restrict__ enc, const float* __restrict__ encT2,
    const float* __restrict__ WihT, const float* __restrict__ WhhT,
    const float* __restrict__ W2T,
    const float* __restrict__ bih, const float* __restrict__ bhh,
    const float* __restrict__ v,
    KeyArgs keys, uint32_t* __restrict__ slots, float* __restrict__ out) {
  __shared__ float2 xh[H];                  // (dec_input, hx) packed
  __shared__ float cs[H];
  __shared__ float2 dv[H];                  // (dec_trans, v) packed
  __shared__ __align__(16) float bsum[G4];  // b_ih + b_hh
  __shared__ __align__(16) float p1arr[2][2][G4];  // [m][hh][j] gate partials
  __shared__ float pdt[4][H];               // init-mean partials
  __shared__ float ps[2][256];              // score k-split partials
  __shared__ float sc[256];                 // masked scores (my half)
  __shared__ float wr_z[4], wr_s[4];
  __shared__ int wr_i[4];
  __shared__ int s_idx;
  __shared__ float outb[2][T];              // deferred outputs (nh==0 only)

  const int tid = threadIdx.x;
  const int bq = blockIdx.x & 127;   // batch
  const int nh = blockIdx.x >> 7;    // n-half: nodes [nh*256, nh*256+256)
  const int lane = tid & 63;
  const int wave = tid >> 6;

  // ---- init: mean partials (round-2 association), bsum, cs/dv --------------
  {
    int h = tid & 127, part = tid >> 7;
    float s = 0.f;
    const float* p = enc + ((size_t)bq * N + part * 128) * H + h;
#pragma unroll 8
    for (int n = 0; n < 128; ++n) s += p[(size_t)n * H];  // coalesced across h
    pdt[part][h] = s;
    bsum[tid] = bih[tid] + bhh[tid];
  }
  if (tid < 128) { cs[tid] = 0.f; dv[tid] = make_float2(0.f, v[tid]); }
  // ---- er: 64 t-invariant encT2 values per thread -> registers -------------
  float er[64];
  {
    const int kh = tid >> 8, nn = tid & 255;
    const float* ep = encT2 + (size_t)bq * (H * N) + (size_t)(kh * 64) * N
                      + nh * 256 + nn;
#pragma unroll
    for (int kk = 0; kk < 64; ++kk) er[kk] = ep[(size_t)kk * N];
  }
  __syncthreads();
  if (tid < 128)
    xh[tid] = make_float2(
        (pdt[0][tid] + pdt[1][tid] + pdt[2][tid] + pdt[3][tid]) * (1.0f / N), 0.f);
  bool masked = false;  // thread tid<256 owns node nh*256+tid
  __syncthreads();

  uint32_t* my = slots + (((size_t)nh * 128 + bq) << 3);
  uint32_t* th = slots + (((size_t)(nh ^ 1) * 128 + bq) << 3);

  for (int t = 0; t < T; ++t) {
    // --- P1: gate partials, float4 weights. thread=(m, hh, j4): 4 gates,
    //     64 h. acc_c = old a0/a1 exactly (sequential h in half) -------------
    {
      const int j4 = tid & 127, hh = (tid >> 7) & 1, m = tid >> 8;
      const float* WT = m ? WhhT : WihT;
      const float4* w4 = (const float4*)(WT + (size_t)(hh * 64) * G4) + j4;
      float a0 = 0.f, a1 = 0.f, a2 = 0.f, a3 = 0.f;
#pragma unroll 8
      for (int h = 0; h < 64; ++h) {
        float4 w = w4[h * 128];                       // 1 KB/wave coalesced
        float2 xv = xh[hh * 64 + h];                  // broadcast
        float x = m ? xv.y : xv.x;
        a0 += w.x * x; a1 += w.y * x; a2 += w.z * x; a3 += w.w * x;
      }
      ((float4*)&p1arr[m][hh][0])[j4] = make_float4(a0, a1, a2, a3);
    }
    __syncthreads();
    // --- P23 (wave 0 only): cell update + dt GEMV in one phase --------------
    if (wave == 0) {
#pragma unroll
      for (int hh2 = 0; hh2 < 2; ++hh2) {
        const int h = hh2 * 64 + lane;
        // gates = ((ih0+hh0) + (ih1+hh1)) + bsum  == rounds 2-5 bit-exact
        float gi = (p1arr[0][0][h] + p1arr[1][0][h])
                 + (p1arr[0][1][h] + p1arr[1][1][h]) + bsum[h];
        float gf = (p1arr[0][0][H + h] + p1arr[1][0][H + h])
                 + (p1arr[0][1][H + h] + p1arr[1][1][H + h]) + bsum[H + h];
        float gg = (p1arr[0][0][2 * H + h] + p1arr[1][0][2 * H + h])
                 + (p1arr[0][1][2 * H + h] + p1arr[1][1][2 * H + h]) + bsum[2 * H + h];
        float go = (p1arr[0][0][3 * H + h] + p1arr[1][0][3 * H + h])
                 + (p1arr[0][1][3 * H + h] + p1arr[1][1][3 * H + h]) + bsum[3 * H + h];
        gi = 1.0f / (1.0f + expf(-gi));
        gf = 1.0f / (1.0f + expf(-gf));
        gg = tanhf(gg);
        go = 1.0f / (1.0f + expf(-go));
        float c = gf * cs[h] + gi * gg;
        cs[h] = c;
        xh[h].y = go * tanhf(c);
      }
      // DS ops of one wave complete in order; block compiler reordering and
      // drain LDS before the cross-lane reads below.
      __asm__ __volatile__("s_waitcnt lgkmcnt(0)" ::: "memory");
      // dt GEMV: thread k2=lane owns cols 2k2,2k2+1; per-part accs preserve
      // the old pdt[part] association: ((p0+p1)+p2)+p3
      const int k2 = lane;
      float q0[4], q1[4];
#pragma unroll
      for (int part = 0; part < 4; ++part) {
        float u0 = 0.f, u1 = 0.f;
#pragma unroll 8
        for (int h = 0; h < 32; ++h) {
          const int hg = part * 32 + h;
          float2 w2v = *(const float2*)&W2T[(size_t)hg * H + 2 * k2];
          float hv = xh[hg].y;
          u0 += w2v.x * hv;
          u1 += w2v.y * hv;
        }
        q0[part] = u0; q1[part] = u1;
      }
      dv[2 * k2].x     = ((q0[0] + q0[1]) + q0[2]) + q0[3];
      dv[2 * k2 + 1].x = ((q1[0] + q1[1]) + q1[2]) + q1[3];
    }
    __syncthreads();
    // --- P4: scores for my 256 n (thread = kh*256+nn), er in regs ----------
    {
      const int kh = tid >> 8, nn = tid & 255;
      const int kb = kh * 64;
      float a0 = 0.f, a1 = 0.f;
#pragma unroll
      for (int kk = 0; kk < 64; kk += 2) {
        float2 d0 = dv[kb + kk];
        float2 d1 = dv[kb + kk + 1];
        a0 += d0.y * fast_tanh(er[kk] + d0.x);
        a1 += d1.y * fast_tanh(er[kk + 1] + d1.x);
      }
      ps[kh][nn] = a0 + a1;   // rounds 2-5 association
    }
    __syncthreads();
    // --- P5: mask + gumbel + per-wave argmax + unshifted expsum (waves 0-3) -
    if (tid < 256) {
      const int ng = nh * 256 + tid;
      float s = masked ? -INFINITY : (ps[0][tid] + ps[1][tid]);
      sc[tid] = s;
      uint32_t bits = gumbel_bits(keys.k[2 * t], keys.k[2 * t + 1], bq * N + ng);
      float f = __uint_as_float((bits >> 9) | 0x3f800000u) - 1.0f;
      float u = fmaxf(TINYF, f + TINYF);
      float g = -logf(-logf(u));  // same instr sequence as rounds 1-5
      float z = s + g;
      int zi = ng;
#pragma unroll
      for (int d = 32; d >= 1; d >>= 1) {
        float oz = __shfl_xor(z, d);
        int oi = __shfl_xor(zi, d);
        if (oz > z || (oz == z && oi < zi)) { z = oz; zi = oi; }  // first-idx ties
      }
      float e = expf(s);  // bounded scores; exp(-inf)=0 for masked
#pragma unroll
      for (int d = 32; d >= 1; d >>= 1) e += __shfl_xor(e, d);
      if (lane == 0) { wr_z[wave] = z; wr_i[wave] = zi; wr_s[wave] = e; }
    }
    __syncthreads();
    // --- P5b: combine, publish, same-XCD partner handoff, sample ------------
    if (tid == 0) {
      float bz = wr_z[0]; int bi = wr_i[0];
#pragma unroll
      for (int w = 1; w < 4; ++w) {
        if (wr_z[w] > bz || (wr_z[w] == bz && wr_i[w] < bi)) { bz = wr_z[w]; bi = wr_i[w]; }
      }
      float es = ((wr_s[0] + wr_s[1]) + wr_s[2]) + wr_s[3];
      float scat = sc[bi - nh * 256];
      ag_store(my + 0, __float_as_uint(bz));
      ag_store(my + 1, (uint32_t)bi);
      ag_store(my + 2, __float_as_uint(es));
      ag_store(my + 3, __float_as_uint(scat));
      __hip_atomic_store(my + 7, FLAG_BASE + (uint32_t)t,
                         __ATOMIC_RELEASE, __HIP_MEMORY_SCOPE_AGENT);
      while (__hip_atomic_load(th + 7, __ATOMIC_ACQUIRE, __HIP_MEMORY_SCOPE_AGENT)
             != FLAG_BASE + (uint32_t)t)
        __builtin_amdgcn_s_sleep(1);
      float oz = __uint_as_float(ag_load(th + 0));
      int oi = (int)ag_load(th + 1);
      float oes = __uint_as_float(ag_load(th + 2));
      float oscat = __uint_as_float(ag_load(th + 3));
      bool iwin = (bz > oz) || (bz == oz && bi < oi);  // global first-idx ties
      int idx = iwin ? bi : oi;
      s_idx = idx;
      if (nh == 0) {
        float S = es + oes;  // (low half) + (high half): index order
        float p = expf(iwin ? scat : oscat) / S;
        outb[0][t] = (float)idx;
        outb[1][t] = logf(p + 1e-9f);
      }
    }
    __syncthreads();
    // --- P6: mask update + next dec_input -----------------------------------
    if (tid < 256) {
      if (nh * 256 + tid == s_idx) masked = true;
    } else if (tid < 384) {
      xh[tid - 256].x = enc[((size_t)bq * N + s_idx) * H + (tid - 256)];
    }
    __syncthreads();
  }
  // ---- epilogue: flush deferred outputs (nh==0 block only) ----
  if (nh == 0 && tid < T) {
    out[(size_t)bq * T + tid] = outb[0][tid];
    out[(size_t)B * T + (size_t)bq * T + tid] = outb[1][tid];
  }
}

// ---------------------------------------------------------------------------
extern "C" void kernel_launch(void* const* d_in, const int* in_sizes, int n_in,
                              void* d_out, int out_size, void* d_ws, size_t ws_size,
                              hipStream_t stream) {
  (void)in_sizes; (void)n_in; (void)out_size; (void)ws_size;
  const float* enc = (const float*)d_in[0];
  const float* Wih = (const float*)d_in[1];
  const float* Whh = (const float*)d_in[2];
  const float* bih = (const float*)d_in[3];
  const float* bhh = (const float*)d_in[4];
  const float* W1  = (const float*)d_in[5];
  const float* W2  = (const float*)d_in[6];
  const float* v   = (const float*)d_in[7];
  float* out = (float*)d_out;
  float* ws = (float*)d_ws;

  // ws layout (floats): WihT 65536 | WhhT 65536 | W2T 16384 | slots 2048 | encT2
  float* WihT  = ws;
  float* WhhT  = ws + 65536;
  float* W2T   = ws + 131072;
  uint32_t* slots = (uint32_t*)(ws + 147456);  // zeroed by k_setup tail blocks
  float* encT2 = ws + 149504;                  // [b][k][n], ~33.5 MB

  KeyArgs keys = make_subkeys();  // pure host arithmetic: capture-safe

  k_setup<<<1088, 512, 0, stream>>>(enc, W1, Wih, Whh, W2, encT2,
                                    WihT, WhhT, W2T, slots);
  k_decode<<<2 * B, 512, 0, stream>>>(enc, encT2, WihT, WhhT, W2T, bih, bhh, v,
                                      keys, slots, out);
}

// Round 7
// 772.640 us; speedup vs baseline: 1.2947x; 1.2947x over previous
//
#include <hip/hip_runtime.h>
#include <cstdint>
#include <cstddef>

// ---------------------------------------------------------------------------
// Pointer-network decoder: B=128 batches decode T=32 steps over N=512 nodes.
// Round 7: round-5 skeleton (128 blocks x 1024 threads, one batch per CU --
// rounds 3 & 6 proved any 2-block-per-batch split regresses). Changes:
//  - P1 = Wih*x only, float2 weight loads on 512 threads (half the VMEM
//    issues); Whh*h(t) for step t+1 is computed by waves 8-15 during the
//    P5 region (those waves were idle there), pgh(0)=0 == round-5 exactly.
//  - All in-loop barriers are lgkmcnt-only (s_waitcnt lgkmcnt(0); s_barrier):
//    every cross-phase dep in the loop is LDS-carried.
//  - Setup reverted to round-2's k_transpose + k_enc_trans verbatim.
// All idx-feeding arithmetic keeps the round-2/5/6-verified associations:
// gates = (ax0+ah0)+(ax1+ah1)+bsum, per-(j,half) sequential-h sums, round-2
// score k-split/pairing, same threefry/logf sequences, same tie-breaks.
// ---------------------------------------------------------------------------

constexpr int B = 128, N = 512, H = 128, T = 32;
constexpr int G4 = 4 * H;  // 512
constexpr float TINYF = 1.17549435e-38f;  // np.finfo(float32).tiny

// lgkm-only barrier: loop phases communicate exclusively through LDS
#define LBAR() __asm__ __volatile__("s_waitcnt lgkmcnt(0)\n\ts_barrier" ::: "memory")

// ---- JAX threefry2x32 block cipher (20 rounds) ----------------------------
__host__ __device__ inline uint32_t rotl32(uint32_t v, int d) {
  return (v << d) | (v >> (32 - d));
}

__host__ __device__ inline void tf2x32(uint32_t k0, uint32_t k1,
                                       uint32_t x0, uint32_t x1,
                                       uint32_t& o0, uint32_t& o1) {
  uint32_t ks2 = k0 ^ k1 ^ 0x1BD11BDAu;
  x0 += k0; x1 += k1;
#define TF_R(r) x0 += x1; x1 = rotl32(x1, (r)); x1 ^= x0;
  TF_R(13) TF_R(15) TF_R(26) TF_R(6)
  x0 += k1; x1 += ks2 + 1u;
  TF_R(17) TF_R(29) TF_R(16) TF_R(24)
  x0 += ks2; x1 += k0 + 2u;
  TF_R(13) TF_R(15) TF_R(26) TF_R(6)
  x0 += k0; x1 += k1 + 3u;
  TF_R(17) TF_R(29) TF_R(16) TF_R(24)
  x0 += k1; x1 += ks2 + 4u;
  TF_R(13) TF_R(15) TF_R(26) TF_R(6)
  x0 += ks2; x1 += k0 + 5u;
#undef TF_R
  o0 = x0; o1 = x1;
}

struct KeyArgs { uint32_t k[2 * T]; };  // per-step subkeys, 256 B by value

// Host-side key chain (partitionable split): key0 = (0,42);
// new_key = E_key(0,0), sub = E_key(0,1).
static KeyArgs make_subkeys() {
  KeyArgs ka;
  uint32_t k0 = 0u, k1 = 42u;
  for (int t = 0; t < T; ++t) {
    uint32_t n0, n1, s0, s1;
    tf2x32(k0, k1, 0u, 0u, n0, n1);
    tf2x32(k0, k1, 0u, 1u, s0, s1);
    ka.k[2 * t] = s0; ka.k[2 * t + 1] = s1;
    k0 = n0; k1 = n1;
  }
  return ka;
}

// 32-bit draw i (of 65536) for this step's subkey: w0^w1 of E_sub(0, i)
__device__ inline uint32_t gumbel_bits(uint32_t sk0, uint32_t sk1, int i) {
  uint32_t o0, o1;
  tf2x32(sk0, sk1, 0u, (uint32_t)i, o0, o1);
  return o0 ^ o1;
}

// fast tanh for the score hot loop; abs err ~2e-7 (clamp avoids inf/inf NaN)
__device__ inline float fast_tanh(float x) {
  float cx = fminf(9.0f, fmaxf(-9.0f, x));
  float t = __expf(2.0f * cx);
  return (t - 1.0f) * __builtin_amdgcn_rcpf(t + 1.0f);
}

// ---- setup kernel 1 (round-2 verbatim): weight transposes ------------------
__global__ void k_transpose(const float* __restrict__ Wih, const float* __restrict__ Whh,
                            const float* __restrict__ W2, const float* __restrict__ W1,
                            float* __restrict__ WihT, float* __restrict__ WhhT,
                            float* __restrict__ W2T, float* __restrict__ W1T) {
  int i = blockIdx.x * blockDim.x + threadIdx.x;
  if (i < H * G4) {
    int h = i >> 9, j = i & (G4 - 1);
    WihT[i] = Wih[j * H + h];
  } else if (i < 2 * H * G4) {
    int q = i - H * G4; int h = q >> 9, j = q & (G4 - 1);
    WhhT[q] = Whh[j * H + h];
  } else if (i < 2 * H * G4 + H * H) {
    int q = i - 2 * H * G4; int h = q >> 7, k = q & (H - 1);
    W2T[q] = W2[k * H + h];
  } else if (i < 2 * H * G4 + 2 * H * H) {
    int q = i - 2 * H * G4 - H * H; int h = q >> 7, k = q & (H - 1);
    W1T[q] = W1[k * H + h];
  }
}

// ---- setup kernel 2 (round-2 verbatim): encT2[b,k,n] = enc[b,n,:]·W1[k,:] --
__global__ __launch_bounds__(256) void k_enc_trans(const float* __restrict__ enc,
                                                   const float* __restrict__ W1T,
                                                   float* __restrict__ encT2) {
  __shared__ __align__(16) float es[16 * 128];  // 8 KB
  int blk = blockIdx.x;
  int b = blk >> 5;               // 32 blocks per batch
  int n0 = (blk & 31) << 4;       // 16 rows
  const float* src = enc + ((size_t)b * N + n0) * H;
  for (int i = threadIdx.x; i < 16 * 128; i += 256) es[i] = src[i];
  __syncthreads();
  int k = threadIdx.x & 127, ng = threadIdx.x >> 7;
  float acc[8] = {0.f, 0.f, 0.f, 0.f, 0.f, 0.f, 0.f, 0.f};
  for (int h = 0; h < H; h += 4) {
    float w0 = W1T[(h + 0) * H + k];   // coalesced (lanes = consecutive k)
    float w1 = W1T[(h + 1) * H + k];
    float w2 = W1T[(h + 2) * H + k];
    float w3 = W1T[(h + 3) * H + k];
#pragma unroll
    for (int j = 0; j < 8; ++j) {
      const float4 e = *(const float4*)&es[(ng * 8 + j) * 128 + h];  // broadcast
      acc[j] += w0 * e.x + w1 * e.y + w2 * e.z + w3 * e.w;
    }
  }
  float* dst = encT2 + (size_t)b * H * N + (size_t)k * N + n0 + ng * 8;
  ((float4*)dst)[0] = make_float4(acc[0], acc[1], acc[2], acc[3]);
  ((float4*)dst)[1] = make_float4(acc[4], acc[5], acc[6], acc[7]);
}

// ---- main fused decoder: 1 block per batch, 1024 threads ------------------
__global__ __launch_bounds__(1024, 4) void k_decode(
    const float* __restrict__ enc, const float* __restrict__ encT2,
    const float* __restrict__ WihT, const float* __restrict__ WhhT,
    const float* __restrict__ W2T,
    const float* __restrict__ bih, const float* __restrict__ bhh,
    const float* __restrict__ v,
    KeyArgs keys, float* __restrict__ out) {
  __shared__ float2 xh[H];                  // (dec_input, hx) packed
  __shared__ float cs[H];
  __shared__ float2 dv[H];                  // (dec_trans, v) packed
  __shared__ __align__(16) float bsum[G4];  // b_ih + b_hh
  __shared__ float pgx[2][G4];              // Wih·x partials  [h-half][j]
  __shared__ float pgh[2][G4];              // Whh·h partials  [h-half][j]
  __shared__ float pdt[4][H];               // dt partials (and init-mean)
  __shared__ float ps[2][N];                // score k-split partials
  __shared__ float sc[N];                   // masked scores
  __shared__ float gb[T * N];               // gumbel table, 64 KB
  __shared__ float wr_z[8], wr_s[8];
  __shared__ int wr_i[8];
  __shared__ float outb[2][T];              // deferred outputs

  const int tid = threadIdx.x;
  const int b = blockIdx.x;
  const int lane = tid & 63;
  const int wave = tid >> 6;
  const int kh = tid >> 9;      // P4 k-half
  const int nn = tid & 511;     // owned score n

  // ---- init-mean partials (round-2 association) ----
  if (tid < 512) {
    int h = tid & 127, part = tid >> 7;
    float s = 0.f;
    const float* p = enc + ((size_t)b * N + part * 128) * H + h;
#pragma unroll 8
    for (int n = 0; n < 128; ++n) s += p[(size_t)n * H];  // coalesced across h
    pdt[part][h] = s;
    bsum[tid] = bih[tid] + bhh[tid];
  }
  ((float*)pgh)[tid] = 0.f;  // pgh(0) = Whh·0 = 0 exactly (== round-5 a1)
  // ---- gumbel table: all (t,n) for this batch (round-5-verified) ----
#pragma unroll
  for (int q = 0; q < 16; ++q) {
    int idx = q * 1024 + tid;           // 0..16383
    int tt = idx >> 9, n = idx & 511;   // tt wave-uniform (64 | 512)
    uint32_t bits = gumbel_bits(keys.k[2 * tt], keys.k[2 * tt + 1], b * N + n);
    // XLA uniform(minval=tiny, maxval=1): bits->[1,2)->-1, +tiny, max
    float f = __uint_as_float((bits >> 9) | 0x3f800000u) - 1.0f;
    float u = fmaxf(TINYF, f + TINYF);
    gb[tt * N + n] = -logf(-logf(u));   // same instr sequence as rounds 1-6
  }
  if (tid < 128) { cs[tid] = 0.f; dv[tid] = make_float2(0.f, v[tid]); }
  // ---- er: this thread's 64 t-invariant encT2 values -> registers ----
  float er[64];
  {
    const float* ep = encT2 + (size_t)b * (H * N) + (size_t)(kh * 64) * N + nn;
#pragma unroll
    for (int kk = 0; kk < 64; ++kk) er[kk] = ep[(size_t)kk * N];
  }
  __syncthreads();
  if (tid < 128)
    xh[tid] = make_float2(
        (pdt[0][tid] + pdt[1][tid] + pdt[2][tid] + pdt[3][tid]) * (1.0f / N), 0.f);
  bool masked = false;  // thread nn (tid<512) owns node nn
  __syncthreads();

  for (int t = 0; t < T; ++t) {
    // --- P1: pgx = Wih·x only. 512 threads, float2 weights.
    //     thread (j2, hh): 2 gates j=2j2,2j2+1, 64 sequential h ->
    //     per-(j,half) sum identical to rounds 2-6 ---------------------------
    if (tid < 512) {
      const int j2 = tid & 255, hhf = tid >> 8;
      const float2* w2p = (const float2*)(WihT + (size_t)(hhf * 64) * G4) + j2;
      float a0 = 0.f, a1 = 0.f;
#pragma unroll 8
      for (int h = 0; h < 64; ++h) {
        float2 w = w2p[h * 256];           // coalesced 512B/wave
        float x = xh[hhf * 64 + h].x;      // broadcast
        a0 += w.x * x; a1 += w.y * x;
      }
      ((float2*)&pgx[hhf][0])[j2] = make_float2(a0, a1);
    }
    LBAR();
    // --- P2: cell update; gates = (ax0+ah0)+(ax1+ah1)+b (round-6-verified) --
    if (tid < 128) {
      float gi = (pgx[0][tid] + pgh[0][tid])
               + (pgx[1][tid] + pgh[1][tid]) + bsum[tid];
      float gf = (pgx[0][H + tid] + pgh[0][H + tid])
               + (pgx[1][H + tid] + pgh[1][H + tid]) + bsum[H + tid];
      float gg = (pgx[0][2 * H + tid] + pgh[0][2 * H + tid])
               + (pgx[1][2 * H + tid] + pgh[1][2 * H + tid]) + bsum[2 * H + tid];
      float go = (pgx[0][3 * H + tid] + pgh[0][3 * H + tid])
               + (pgx[1][3 * H + tid] + pgh[1][3 * H + tid]) + bsum[3 * H + tid];
      gi = 1.0f / (1.0f + expf(-gi));
      gf = 1.0f / (1.0f + expf(-gf));
      gg = tanhf(gg);
      go = 1.0f / (1.0f + expf(-go));
      float c = gf * cs[tid] + gi * gg;
      cs[tid] = c;
      xh[tid].y = go * tanhf(c);
    }
    LBAR();
    // --- P3a: dt partials (k = tid&127, 32 h each); round-2 assoc -----------
    if (tid < 512) {
      int k = tid & 127, part = tid >> 7;
      const float* w2 = W2T + (size_t)(part * 32) * H + k;
      const int hb = part * 32;
      float a = 0.f;
#pragma unroll 8
      for (int h = 0; h < 32; ++h) a += w2[h * H] * xh[hb + h].y;
      pdt[part][k] = a;
    }
    LBAR();
    // --- P3b: dt reduce -----------------------------------------------------
    if (tid < 128)
      dv[tid].x = pdt[0][tid] + pdt[1][tid] + pdt[2][tid] + pdt[3][tid];
    LBAR();
    // --- P4: scores, pure VALU (er in regs, dv broadcast); round-2 assoc ----
    {
      const int kb = kh * 64;
      float a0 = 0.f, a1 = 0.f;
#pragma unroll
      for (int kk = 0; kk < 64; kk += 2) {
        float2 d0 = dv[kb + kk];
        float2 d1 = dv[kb + kk + 1];
        a0 += d0.y * fast_tanh(er[kk] + d0.x);
        a1 += d1.y * fast_tanh(er[kk + 1] + d1.x);
      }
      ps[kh][nn] = a0 + a1;
    }
    LBAR();
    // --- P5: waves 0-7: mask + gumbel + argmax + expsum;
    //         waves 8-15: pgh(t+1) = Whh·h(t)  (pipelined off critical path) -
    if (tid < 512) {
      float s = masked ? -INFINITY : (ps[0][tid] + ps[1][tid]);
      sc[tid] = s;
      float z = s + gb[t * N + tid];
      int zi = tid;
#pragma unroll
      for (int d = 32; d >= 1; d >>= 1) {
        float oz = __shfl_xor(z, d);
        int oi = __shfl_xor(zi, d);
        if (oz > z || (oz == z && oi < zi)) { z = oz; zi = oi; }  // first-idx ties
      }
      float e = expf(s);  // scores bounded (|s|<~6): no shift needed; exp(-inf)=0
#pragma unroll
      for (int d = 32; d >= 1; d >>= 1) e += __shfl_xor(e, d);
      if (lane == 0) { wr_z[wave] = z; wr_i[wave] = zi; wr_s[wave] = e; }
    } else {
      const int u = tid - 512;
      const int j2 = u & 255, hhf = u >> 8;
      const float2* w2p = (const float2*)(WhhT + (size_t)(hhf * 64) * G4) + j2;
      float a0 = 0.f, a1 = 0.f;
#pragma unroll 8
      for (int h = 0; h < 64; ++h) {
        float2 w = w2p[h * 256];
        float hv = xh[hhf * 64 + h].y;     // h(t), stable since P2's barrier
        a0 += w.x * hv; a1 += w.y * hv;
      }
      ((float2*)&pgh[hhf][0])[j2] = make_float2(a0, a1);
    }
    LBAR();
    // --- P6: redundant combine (all threads), mask, xs gather, outputs ------
    {
      float bz = wr_z[0]; int bi = wr_i[0];
#pragma unroll
      for (int w = 1; w < 8; ++w) {
        float wz = wr_z[w]; int wj = wr_i[w];
        if (wz > bz || (wz == bz && wj < bi)) { bz = wz; bi = wj; }
      }
      if (tid == bi) masked = true;  // owner thread (tid<512)
      if (tid >= 512 && tid < 640)
        xh[tid - 512].x = enc[((size_t)b * N + bi) * H + (tid - 512)];
      if (tid == 0) {
        float S = ((((((wr_s[0] + wr_s[1]) + wr_s[2]) + wr_s[3]) + wr_s[4])
                    + wr_s[5]) + wr_s[6]) + wr_s[7];
        float p = expf(sc[bi]) / S;
        outb[0][t] = (float)bi;
        outb[1][t] = logf(p + 1e-9f);  // LDS write: no global drain at barrier
      }
    }
    LBAR();
  }
  // ---- epilogue: flush deferred outputs ----
  if (tid < T) {
    out[(size_t)b * T + tid] = outb[0][tid];
    out[(size_t)B * T + (size_t)b * T + tid] = outb[1][tid];
  }
}

// ---------------------------------------------------------------------------
extern "C" void kernel_launch(void* const* d_in, const int* in_sizes, int n_in,
                              void* d_out, int out_size, void* d_ws, size_t ws_size,
                              hipStream_t stream) {
  (void)in_sizes; (void)n_in; (void)out_size; (void)ws_size;
  const float* enc = (const float*)d_in[0];
  const float* Wih = (const float*)d_in[1];
  const float* Whh = (const float*)d_in[2];
  const float* bih = (const float*)d_in[3];
  const float* bhh = (const float*)d_in[4];
  const float* W1  = (const float*)d_in[5];
  const float* W2  = (const float*)d_in[6];
  const float* v   = (const float*)d_in[7];
  float* out = (float*)d_out;
  float* ws = (float*)d_ws;

  // ws layout (floats): WihT 65536 | WhhT 65536 | W2T 16384 | W1T 16384 | encT2
  float* WihT  = ws;
  float* WhhT  = ws + 65536;
  float* W2T   = ws + 131072;
  float* W1T   = ws + 147456;
  float* encT2 = ws + 163840;   // [b][k][n], ~33.5 MB

  KeyArgs keys = make_subkeys();  // pure host arithmetic: capture-safe

  k_transpose<<<640, 256, 0, stream>>>(Wih, Whh, W2, W1, WihT, WhhT, W2T, W1T);
  k_enc_trans<<<B * N / 16, 256, 0, stream>>>(enc, W1T, encT2);
  k_decode<<<B, 1024, 0, stream>>>(enc, encT2, WihT, WhhT, W2T, bih, bhh, v,
                                   keys, out);
}